// Round 3
// baseline (490.884 us; speedup 1.0000x reference)
//
#include <hip/hip_runtime.h>
#include <cstdint>
#include <cstddef>

// Problem constants (fixed by the reference)
#define HW    16384
#define CCH   256
#define WID   128
#define NB    8
#define NSEL  500
#define NPAD  512
#define CPG   16     // channels per gather block

// ---------- helpers ----------
__device__ __forceinline__ unsigned key_of(float f) {
  // monotone float->uint map (larger float -> larger uint); logits are finite
  unsigned u = __float_as_uint(f);
  return (u & 0x80000000u) ? ~u : (u | 0x80000000u);
}

// ---------- K1: saliency logits + full x_main -> out copy (single read pass) ----------
// The copy here removes final_kernel's dense 536 MB read + 536 MB write pass;
// nontemporal stores keep LLC warmer for the gather that follows.
__global__ __launch_bounds__(256) void score_copy_kernel(const float* __restrict__ x,
                                                         const float* __restrict__ w,
                                                         float* __restrict__ logits,
                                                         float* __restrict__ out) {
  __shared__ float ws[CCH];
  int tid = threadIdx.x;
  ws[tid] = w[tid];
  __syncthreads();
  int pix = blockIdx.x * 256 + tid;            // 0 .. B*HW-1
  int b = pix >> 14, p = pix & (HW - 1);
  const float* xp = x + ((size_t)b << 22) + p; // b*C*HW
  float* op = out + ((size_t)b << 22) + p;
  float acc = 0.f;
#pragma unroll 8
  for (int c = 0; c < CCH; c++) {
    float v = xp[(size_t)c * HW];
    acc += v * ws[c];
    __builtin_nontemporal_store(v, &op[(size_t)c * HW]);
  }
  logits[pix] = acc;
}

// ---------- K2: per-batch top-500, 1024 threads, keys in registers ----------
// Scans done with wave-level shfl (wave=64). map[] no longer produced (sparse final).
__global__ __launch_bounds__(1024) void topk_kernel(const float* __restrict__ logits,
                                                    int* __restrict__ idx_out) {
  int b = blockIdx.x, tid = threadIdx.x;
  int lane = tid & 63, wave = tid >> 6;
  const float* lg = logits + (size_t)b * HW;
  __shared__ unsigned hist[256];
  __shared__ unsigned wtot[4];
  __shared__ unsigned wsum[16];
  __shared__ unsigned bc_prefix;
  __shared__ int bc_want;
  __shared__ int cnt;

  // each thread owns 16 CONSECUTIVE indices [tid*16, tid*16+16) in registers
  unsigned kreg[16];
#pragma unroll
  for (int j = 0; j < 4; j++) {
    float4 v = *(const float4*)&lg[tid * 16 + j * 4];
    kreg[4 * j + 0] = key_of(v.x);
    kreg[4 * j + 1] = key_of(v.y);
    kreg[4 * j + 2] = key_of(v.z);
    kreg[4 * j + 3] = key_of(v.w);
  }

  unsigned prefix = 0;
  int want = NSEL;
  for (int shift = 24; shift >= 0; shift -= 8) {
    if (tid < 256) hist[tid] = 0;
    __syncthreads();
#pragma unroll
    for (int j = 0; j < 16; j++) {
      unsigned u = kreg[j];
      bool m = (shift == 24) || ((u >> (shift + 8)) == (prefix >> (shift + 8)));
      if (m) atomicAdd(&hist[(u >> shift) & 255u], 1u);
    }
    __syncthreads();
    // suffix-sum over 256 bins: waves 0..3 hold 64 bins each, shfl suffix scan
    unsigned h = (tid < 256) ? hist[tid] : 0u;
    unsigned v = h;
#pragma unroll
    for (int o = 1; o < 64; o <<= 1) {
      unsigned t = __shfl_down(v, o);
      if (lane < 64 - o) v += t;
    }
    if (tid < 256 && lane == 0) wtot[wave] = v;  // wave total = suffix at lane 0
    __syncthreads();
    if (tid < 256) {
      unsigned sfx = v;
      for (int w2 = wave + 1; w2 < 4; w2++) sfx += wtot[w2];
      unsigned above = sfx - h;  // count strictly above this bin
      if ((int)sfx >= want && (int)above < want) {  // exactly one tid
        bc_prefix = prefix | ((unsigned)tid << shift);
        bc_want = want - (int)above;
      }
    }
    __syncthreads();
    prefix = bc_prefix;
    want = bc_want;
    // (next write of bc_prefix is 3 barriers away -> safe to read without extra barrier)
  }
  unsigned thr = prefix;  // exact key of boundary element; take `want` ties by lowest index

  int local = 0;
#pragma unroll
  for (int j = 0; j < 16; j++) local += (kreg[j] == thr) ? 1 : 0;
  // wave-level inclusive prefix scan of `local` over tid order
  unsigned pv = (unsigned)local;
#pragma unroll
  for (int o = 1; o < 64; o <<= 1) {
    unsigned t = __shfl_up(pv, o);
    if (lane >= o) pv += t;
  }
  if (lane == 63) wsum[wave] = pv;  // wave total
  if (tid == 0) cnt = 0;
  __syncthreads();
  unsigned woff = 0;
  for (int w2 = 0; w2 < wave; w2++) woff += wsum[w2];
  int rank = (int)(woff + pv) - local;  // exclusive prefix over tid*16+j order
#pragma unroll
  for (int j = 0; j < 16; j++) {
    unsigned u = kreg[j];
    bool take = (u > thr);
    if (u == thr) { if (rank < want) take = true; rank++; }
    if (take) {
      int s = atomicAdd(&cnt, 1);
      idx_out[b * NPAD + s] = tid * 16 + j;
    }
  }
}

// ---------- shared patch-weight computation ----------
__device__ __forceinline__ void patch_weights(int p, int* xc, int* yc, float* wx, float* wy) {
  int iy = p >> 7, ix = p & (WID - 1);
#pragma unroll
  for (int d = 0; d < 7; d++) {
    int t = ix + d - 3;
    bool in = (t >= 0) && (t < WID);
    xc[d] = in ? t : (t < 0 ? 0 : WID - 1);
    wx[d] = in ? 1.f : 0.5f;
    t = iy + d - 3;
    in = (t >= 0) && (t < WID);
    yc[d] = in ? t : (t < 0 ? 0 : WID - 1);
    wy[d] = in ? 1.f : 0.5f;
  }
}

// ---------- K3: DMA double-buffered plane gather ----------
// grid (CCH/CPG, B, 2feat), 512 threads, 128 KB dynamic LDS (two plane buffers).
// global_load_lds (width 16) DMAs plane c+1 into buf^1 while waves gather plane c
// from buf via ds_read; the single __syncthreads' vmcnt(0)-drain is the pipe wait.
__global__ __launch_bounds__(512) void gather_dma_kernel(const float* __restrict__ xm,
                                                         const float* __restrict__ xa,
                                                         const int* __restrict__ idx,
                                                         float* __restrict__ vmainT,
                                                         float* __restrict__ vauxT) {
  extern __shared__ float plane2[];  // 2 * HW floats = 128 KB
  int g = blockIdx.x, b = blockIdx.y, z = blockIdx.z;
  int tid = threadIdx.x;
  int c0 = g * CPG;
  const float* src = (z == 0 ? xm : xa) + ((size_t)(b * CCH + c0)) * HW;
  float* dst = (z == 0 ? vmainT : vauxT) + (((size_t)(b * CCH + c0)) << 9);

  // per-point patch geometry, once per block (same point set for all channels)
  int t500 = (tid < NSEL) ? tid : 0;
  int p = idx[b * NPAD + t500];
  float wx[7], wy[7];
  int xc[7], yc[7], rb[7];
  patch_weights(p, xc, yc, wx, wy);
#pragma unroll
  for (int d = 0; d < 7; d++) rb[d] = yc[d] * WID;

  // prologue: DMA plane 0 into buffer 0
#pragma unroll
  for (int j = 0; j < 8; j++) {
    int off = (tid + j * 512) * 4;
    __builtin_amdgcn_global_load_lds(
        (const __attribute__((address_space(1))) float*)(src + off),
        (__attribute__((address_space(3))) float*)(plane2 + off), 16, 0, 0);
  }
  __syncthreads();  // drains vmcnt(0): plane 0 resident

  for (int c = 0; c < CPG; c++) {
    float* cur = plane2 + ((c & 1) ? HW : 0);
    float* nxt = plane2 + ((c & 1) ? 0 : HW);
    if (c + 1 < CPG) {
      // issue next plane's DMA: flies under the gather below
      const float* s2 = src + (size_t)(c + 1) * HW;
#pragma unroll
      for (int j = 0; j < 8; j++) {
        int off = (tid + j * 512) * 4;
        __builtin_amdgcn_global_load_lds(
            (const __attribute__((address_space(1))) float*)(s2 + off),
            (__attribute__((address_space(3))) float*)(nxt + off), 16, 0, 0);
      }
    }
    // gather current plane from LDS
    if (tid < NSEL) {
      float s = 0.f, mx = -INFINITY;
#pragma unroll
      for (int dy = 0; dy < 7; dy++) {
        float rs = 0.f, rm = -INFINITY;
        int rbb = rb[dy];
        float wyd = wy[dy];
#pragma unroll
        for (int dx = 0; dx < 7; dx++) {
          float v = cur[rbb + xc[dx]] * wx[dx];
          rs += v;
          rm = fmaxf(rm, v);
        }
        s += rs * wyd;
        mx = fmaxf(mx, rm * wyd);
      }
      dst[((size_t)c << 9) + tid] = 0.5f * (s * (1.f / 49.f) + mx);
    } else {
      dst[((size_t)c << 9) + tid] = 0.f;  // zero pad rows: no 0*garbage downstream
    }
    __syncthreads();  // all waves done with cur; nxt DMA drained (vmcnt(0))
  }
}

// ---------- tiled fp32 GEMM: C[b] = A[b](MxK) * B(KxN) ----------
// AT: A stored K-major (KxM). BT: B stored transposed (NxK). BSHARED: B not batched.
// EPI 0: plain store; 1: *0.0625; 2: +bias[col], store transposed [b][N][M]
// LDS layout: As is k-major [BK][BM+4], Bs is [BK][BN+4] -> both fragment reads
// are single 16B-aligned ds_read_b128.
template <int M, int N, int K, bool AT, bool BT, bool BSHARED, int EPI>
__global__ __launch_bounds__(256) void gemm_kernel(const float* __restrict__ A,
                                                   const float* __restrict__ B,
                                                   float* __restrict__ C,
                                                   const float* __restrict__ bias) {
  constexpr int BM = 64, BN = 64, BK = 16;
  __shared__ float As[BK][BM + 4];
  __shared__ float Bs[BK][BN + 4];
  int tid = threadIdx.x;
  int bx = blockIdx.x, by = blockIdx.y, b = blockIdx.z;
  const float* Ab = A + (size_t)b * M * K;
  const float* Bb = BSHARED ? B : (B + (size_t)b * ((size_t)K * N));
  int tx = tid & 15, ty = tid >> 4;
  float acc[4][4] = {};

  for (int k0 = 0; k0 < K; k0 += BK) {
    if (!AT) {
      // A row-major MxK: row ar, cols k0+ac4..+3  -> scatter into k-major As
      int ar = tid >> 2, ac4 = (tid & 3) * 4;
      const float4 av = *(const float4*)&Ab[(size_t)(by * BM + ar) * K + k0 + ac4];
      As[ac4 + 0][ar] = av.x; As[ac4 + 1][ar] = av.y;
      As[ac4 + 2][ar] = av.z; As[ac4 + 3][ar] = av.w;
    } else {
      // A is KxM: row k0+kr, cols by*BM+mc..+3 -> contiguous float4 LDS write
      int kr = tid >> 4, mc = (tid & 15) * 4;
      *(float4*)&As[kr][mc] = *(const float4*)&Ab[(size_t)(k0 + kr) * M + by * BM + mc];
    }
    if (!BT) {
      int br = tid >> 4, bc4 = (tid & 15) * 4;
      *(float4*)&Bs[br][bc4] = *(const float4*)&Bb[(size_t)(k0 + br) * N + bx * BN + bc4];
    } else {
      // B is NxK: row bx*BN+nr, cols k0+kc4..+3 -> scatter into k-major Bs
      int nr = tid >> 2, kc4 = (tid & 3) * 4;
      const float4 bv = *(const float4*)&Bb[(size_t)(bx * BN + nr) * K + k0 + kc4];
      Bs[kc4 + 0][nr] = bv.x; Bs[kc4 + 1][nr] = bv.y;
      Bs[kc4 + 2][nr] = bv.z; Bs[kc4 + 3][nr] = bv.w;
    }
    __syncthreads();
#pragma unroll
    for (int kk = 0; kk < BK; kk++) {
      const float4 a = *(const float4*)&As[kk][ty * 4];
      const float4 bb = *(const float4*)&Bs[kk][tx * 4];
      float av[4] = {a.x, a.y, a.z, a.w};
      float bv[4] = {bb.x, bb.y, bb.z, bb.w};
#pragma unroll
      for (int rr = 0; rr < 4; rr++)
#pragma unroll
        for (int ss = 0; ss < 4; ss++) acc[rr][ss] += av[rr] * bv[ss];
    }
    __syncthreads();
  }
  if (EPI == 2) {
#pragma unroll
    for (int s = 0; s < 4; s++) {
      int col = bx * BN + tx * 4 + s;
      float bv = bias[col];
#pragma unroll
      for (int r = 0; r < 4; r++) {
        int row = by * BM + ty * 4 + r;
        C[((size_t)b * N + col) * M + row] = acc[r][s] + bv;
      }
    }
  } else {
    float scale = (EPI == 1) ? 0.0625f : 1.f;  // 1/sqrt(256)
#pragma unroll
    for (int r = 0; r < 4; r++) {
      int row = by * BM + ty * 4 + r;
#pragma unroll
      for (int s = 0; s < 4; s++) {
        int col = bx * BN + tx * 4 + s;
        C[((size_t)b * M + row) * N + col] = acc[r][s] * scale;
      }
    }
  }
}

// ---------- softmax over j (masked to j<NSEL), in place ----------
__global__ __launch_bounds__(256) void softmax_kernel(float* __restrict__ sim) {
  int i = blockIdx.x, b = blockIdx.y, tid = threadIdx.x;
  float* row = sim + ((size_t)b * NPAD + i) * NPAD;
  float v0 = (tid < NSEL) ? row[tid] : -INFINITY;
  int j1 = tid + 256;
  float v1 = (j1 < NSEL) ? row[j1] : -INFINITY;
  float m = fmaxf(v0, v1);
  for (int o = 32; o; o >>= 1) m = fmaxf(m, __shfl_down(m, o));
  __shared__ float red[4];
  __shared__ float bm, bs;
  int wave = tid >> 6, lane = tid & 63;
  if (lane == 0) red[wave] = m;
  __syncthreads();
  if (tid == 0) bm = fmaxf(fmaxf(red[0], red[1]), fmaxf(red[2], red[3]));
  __syncthreads();
  m = bm;
  float e0 = (tid < NSEL) ? expf(v0 - m) : 0.f;
  float e1 = (j1 < NSEL) ? expf(v1 - m) : 0.f;
  float s = e0 + e1;
  for (int o = 32; o; o >>= 1) s += __shfl_down(s, o);
  if (lane == 0) red[wave] = s;
  __syncthreads();
  if (tid == 0) bs = 1.f / (red[0] + red[1] + red[2] + red[3]);
  __syncthreads();
  row[tid] = e0 * bs;
  row[j1] = e1 * bs;
}

// ---------- gated-fusion MLP: vfused = vm + gate*(vm - vhat) ----------
// vm from channel-major vmainT[b][c][i]; vhat row-major [b][i][c]
// fc1 reduction via LDS transpose instead of 96 ds_bpermute shuffles.
__global__ __launch_bounds__(256) void mlp_kernel(const float* __restrict__ vmainT,
                                                  const float* __restrict__ vhat,
                                                  const float* __restrict__ fc1w,
                                                  const float* __restrict__ fc1b,
                                                  const float* __restrict__ fc2w,
                                                  const float* __restrict__ fc2b,
                                                  float* __restrict__ vfused) {
  int i = blockIdx.x, b = blockIdx.y, c = threadIdx.x;
  size_t base = ((size_t)b * NPAD + i) * CCH + c;
  float vm = vmainT[(((size_t)(b * CCH + c)) << 9) + i];
  float vh = vhat[base], vd = vm - vh;
  const float* w0 = fc1w + (size_t)c * 16;
  const float* w1 = fc1w + (size_t)(256 + c) * 16;
  const float* w2 = fc1w + (size_t)(512 + c) * 16;
  __shared__ float ph[256][17];    // [c][k], +1 pad: conflict-free both axes
  __shared__ float part2[16][17];  // [group][k]
  __shared__ float hsh[16];
#pragma unroll
  for (int k = 0; k < 16; k++) ph[c][k] = vm * w0[k] + vh * w1[k] + vd * w2[k];
  __syncthreads();
  int kk = c & 15, g = c >> 4;
  float part = 0.f;
#pragma unroll
  for (int j = 0; j < 16; j++) part += ph[g * 16 + j][kk];
  part2[g][kk] = part;
  __syncthreads();
  if (c < 16) {
    float s = fc1b[c];
#pragma unroll
    for (int g2 = 0; g2 < 16; g2++) s += part2[g2][c];
    hsh[c] = fmaxf(s, 0.f);
  }
  __syncthreads();
  float gte = fc2b[c];
#pragma unroll
  for (int k = 0; k < 16; k++) gte += hsh[k] * fc2w[k * 256 + c];
  gte = 1.f / (1.f + expf(-gte));
  vfused[base] = vm + gte * vd;
}

// ---------- K5: sparse scatter out[b,c,pix[s]] += vinjT[b,c,s] ----------
// out already holds the x_main copy (score_copy_kernel). Only ~3% of pixels
// are touched: ~100 MB of line traffic vs the old dense 1073 MB pass.
__global__ __launch_bounds__(256) void scatter_kernel(const int* __restrict__ idx,
                                                      const float* __restrict__ vinjT,
                                                      float* __restrict__ out) {
  int c = blockIdx.x, b = blockIdx.y, t = threadIdx.x;
  float* op = out + ((size_t)(b * CCH + c) << 14);
  const float* vp = vinjT + ((size_t)(b * CCH + c) << 9);
  const int* ib = idx + b * NPAD;
  // s = t (0..255 all valid) and s = t+256 (guard at 500)
  op[ib[t]] += vp[t];
  int s = t + 256;
  if (s < NSEL) op[ib[s]] += vp[s];
}

extern "C" void kernel_launch(void* const* d_in, const int* in_sizes, int n_in,
                              void* d_out, int out_size, void* d_ws, size_t ws_size,
                              hipStream_t stream) {
  const float* x_main   = (const float*)d_in[0];
  const float* x_aux    = (const float*)d_in[1];
  const float* scorer_w = (const float*)d_in[2];
  // d_in[3] scorer_b: constant shift, irrelevant to top-k set -> unused
  const float* fc1_w = (const float*)d_in[4];
  const float* fc1_b = (const float*)d_in[5];
  const float* fc2_w = (const float*)d_in[6];
  const float* fc2_b = (const float*)d_in[7];
  const float* proj_w = (const float*)d_in[8];
  const float* proj_b = (const float*)d_in[9];
  // d_in[10] n == 500 (fixed)
  (void)in_sizes; (void)n_in; (void)out_size; (void)ws_size;

  float* ws = (float*)d_ws;
  // workspace layout (floats), ~26 MB total
  float* logits = ws;                      // 131072
  int*   idx    = (int*)(ws + 131072);     // 4096
  float* vmainT = ws + 266240;             // 1048576  [b][c][i]
  float* vauxT  = ws + 1314816;            // 1048576  [b][c][i]
  float* vhat   = ws + 2363392;            // 1048576  [b][i][c] (v_injT reuses this)
  float* vfused = ws + 3411968;            // 1048576  [b][i][c]
  float* sim    = ws + 4460544;            // 2097152  [b][i][j]
  float* vinjT  = vhat;
  float* out = (float*)d_out;

  score_copy_kernel<<<512, 256, 0, stream>>>(x_main, scorer_w, logits, out);
  topk_kernel<<<NB, 1024, 0, stream>>>(logits, idx);
  gather_dma_kernel<<<dim3(CCH / CPG, NB, 2), 512, 2 * HW * sizeof(float), stream>>>(
      x_main, x_aux, idx, vmainT, vauxT);
  // sim[b][i][j] = sum_c vmainT[b][c][i] * vauxT[b][c][j] / 16   (TN gemm)
  gemm_kernel<NPAD, NPAD, CCH, true, false, false, 1>
      <<<dim3(8, 8, NB), 256, 0, stream>>>(vmainT, vauxT, sim, nullptr);
  softmax_kernel<<<dim3(NPAD, NB), 256, 0, stream>>>(sim);
  // v_hat[b][i][c] = sum_j attn[b][i][j] * vauxT[b][c][j]   (B transposed)
  gemm_kernel<NPAD, CCH, NPAD, false, true, false, 0>
      <<<dim3(4, 8, NB), 256, 0, stream>>>(sim, vauxT, vhat, nullptr);
  mlp_kernel<<<dim3(NPAD, NB), 256, 0, stream>>>(vmainT, vhat, fc1_w, fc1_b,
                                                 fc2_w, fc2_b, vfused);
  // v_injT[b][c][i] = (v_fused @ proj_w + proj_b)^T
  gemm_kernel<NPAD, CCH, CCH, false, false, true, 2>
      <<<dim3(4, 8, NB), 256, 0, stream>>>(vfused, proj_w, vinjT, proj_b);
  scatter_kernel<<<dim3(CCH, NB), 256, 0, stream>>>(idx, vinjT, out);
}

// Round 4
// 486.574 us; speedup vs baseline: 1.0089x; 1.0089x over previous
//
#include <hip/hip_runtime.h>
#include <cstdint>
#include <cstddef>

// Problem constants (fixed by the reference)
#define HW    16384
#define CCH   256
#define WID   128
#define NB    8
#define NSEL  500
#define NPAD  512
#define CPG   16     // channels per gather block

// ---------- helpers ----------
__device__ __forceinline__ unsigned key_of(float f) {
  // monotone float->uint map (larger float -> larger uint); logits are finite
  unsigned u = __float_as_uint(f);
  return (u & 0x80000000u) ? ~u : (u | 0x80000000u);
}

// ---------- K1: saliency logits + full x_main -> out copy (single read pass) ----------
// unroll 32: ~32 outstanding loads/wave (VGPR ~40) to cover ~900cy HBM latency at
// the grid-limited 2 waves/SIMD occupancy. Channel order kept strictly sequential
// so logits are bit-identical to prior rounds (topk set must not flip).
__global__ __launch_bounds__(256) void score_copy_kernel(const float* __restrict__ x,
                                                         const float* __restrict__ w,
                                                         float* __restrict__ logits,
                                                         float* __restrict__ out) {
  __shared__ float ws[CCH];
  int tid = threadIdx.x;
  ws[tid] = w[tid];
  __syncthreads();
  int pix = blockIdx.x * 256 + tid;            // 0 .. B*HW-1
  int b = pix >> 14, p = pix & (HW - 1);
  const float* xp = x + ((size_t)b << 22) + p; // b*C*HW
  float* op = out + ((size_t)b << 22) + p;
  float acc = 0.f;
#pragma unroll 32
  for (int c = 0; c < CCH; c++) {
    float v = xp[(size_t)c * HW];
    acc += v * ws[c];
    __builtin_nontemporal_store(v, &op[(size_t)c * HW]);
  }
  logits[pix] = acc;
}

// ---------- K2: per-batch top-500, 1024 threads, keys in registers ----------
// Per-wave PRIVATIZED histograms: logits ~N(0,1) put ~30% of keys in one top-byte
// bin -> shared-hist atomicAdd serialized ~5000 deep. 16 private hists cut the
// worst-case chain 16x (only intra-wave contention remains).
__global__ __launch_bounds__(1024) void topk_kernel(const float* __restrict__ logits,
                                                    int* __restrict__ idx_out) {
  int b = blockIdx.x, tid = threadIdx.x;
  int lane = tid & 63, wave = tid >> 6;
  const float* lg = logits + (size_t)b * HW;
  __shared__ unsigned histp[16 * 256];  // per-wave private histograms (16 KB)
  __shared__ unsigned wtot[4];
  __shared__ unsigned wsum[16];
  __shared__ unsigned bc_prefix;
  __shared__ int bc_want;
  __shared__ int cnt;

  // each thread owns 16 CONSECUTIVE indices [tid*16, tid*16+16) in registers
  unsigned kreg[16];
#pragma unroll
  for (int j = 0; j < 4; j++) {
    float4 v = *(const float4*)&lg[tid * 16 + j * 4];
    kreg[4 * j + 0] = key_of(v.x);
    kreg[4 * j + 1] = key_of(v.y);
    kreg[4 * j + 2] = key_of(v.z);
    kreg[4 * j + 3] = key_of(v.w);
  }

  unsigned prefix = 0;
  int want = NSEL;
  for (int shift = 24; shift >= 0; shift -= 8) {
#pragma unroll
    for (int q = 0; q < 4; q++) histp[tid + q * 1024] = 0;
    __syncthreads();
    unsigned* myhist = histp + wave * 256;
#pragma unroll
    for (int j = 0; j < 16; j++) {
      unsigned u = kreg[j];
      bool m = (shift == 24) || ((u >> (shift + 8)) == (prefix >> (shift + 8)));
      if (m) atomicAdd(&myhist[(u >> shift) & 255u], 1u);
    }
    __syncthreads();
    // combine 16 private hists for this thread's bin, then shfl suffix-scan
    unsigned h = 0;
    if (tid < 256) {
#pragma unroll
      for (int w2 = 0; w2 < 16; w2++) h += histp[w2 * 256 + tid];
    }
    unsigned v = h;
#pragma unroll
    for (int o = 1; o < 64; o <<= 1) {
      unsigned t = __shfl_down(v, o);
      if (lane < 64 - o) v += t;
    }
    if (tid < 256 && lane == 0) wtot[wave] = v;  // wave total = suffix at lane 0
    __syncthreads();
    if (tid < 256) {
      unsigned sfx = v;
      for (int w2 = wave + 1; w2 < 4; w2++) sfx += wtot[w2];
      unsigned above = sfx - h;  // count strictly above this bin
      if ((int)sfx >= want && (int)above < want) {  // exactly one tid
        bc_prefix = prefix | ((unsigned)tid << shift);
        bc_want = want - (int)above;
      }
    }
    __syncthreads();
    prefix = bc_prefix;
    want = bc_want;
    // (next write of bc_prefix is 2 barriers away -> safe without extra barrier)
  }
  unsigned thr = prefix;  // exact key of boundary element; take `want` ties by lowest index

  int local = 0;
#pragma unroll
  for (int j = 0; j < 16; j++) local += (kreg[j] == thr) ? 1 : 0;
  // wave-level inclusive prefix scan of `local` over tid order
  unsigned pv = (unsigned)local;
#pragma unroll
  for (int o = 1; o < 64; o <<= 1) {
    unsigned t = __shfl_up(pv, o);
    if (lane >= o) pv += t;
  }
  if (lane == 63) wsum[wave] = pv;  // wave total
  if (tid == 0) cnt = 0;
  __syncthreads();
  unsigned woff = 0;
  for (int w2 = 0; w2 < wave; w2++) woff += wsum[w2];
  int rank = (int)(woff + pv) - local;  // exclusive prefix over tid*16+j order
#pragma unroll
  for (int j = 0; j < 16; j++) {
    unsigned u = kreg[j];
    bool take = (u > thr);
    if (u == thr) { if (rank < want) take = true; rank++; }
    if (take) {
      int s = atomicAdd(&cnt, 1);
      idx_out[b * NPAD + s] = tid * 16 + j;
    }
  }
}

// ---------- shared patch-weight computation ----------
__device__ __forceinline__ void patch_weights(int p, int* xc, int* yc, float* wx, float* wy) {
  int iy = p >> 7, ix = p & (WID - 1);
#pragma unroll
  for (int d = 0; d < 7; d++) {
    int t = ix + d - 3;
    bool in = (t >= 0) && (t < WID);
    xc[d] = in ? t : (t < 0 ? 0 : WID - 1);
    wx[d] = in ? 1.f : 0.5f;
    t = iy + d - 3;
    in = (t >= 0) && (t < WID);
    yc[d] = in ? t : (t < 0 ? 0 : WID - 1);
    wy[d] = in ? 1.f : 0.5f;
  }
}

// ---------- K3: DMA double-buffered plane gather ----------
// grid (CCH/CPG, B, 2feat), 512 threads, 128 KB dynamic LDS (two plane buffers).
// global_load_lds (width 16) DMAs plane c+1 into buf^1 while waves gather plane c
// from buf via ds_read; the single __syncthreads' vmcnt(0)-drain is the pipe wait.
__global__ __launch_bounds__(512) void gather_dma_kernel(const float* __restrict__ xm,
                                                         const float* __restrict__ xa,
                                                         const int* __restrict__ idx,
                                                         float* __restrict__ vmainT,
                                                         float* __restrict__ vauxT) {
  extern __shared__ float plane2[];  // 2 * HW floats = 128 KB
  int g = blockIdx.x, b = blockIdx.y, z = blockIdx.z;
  int tid = threadIdx.x;
  int c0 = g * CPG;
  const float* src = (z == 0 ? xm : xa) + ((size_t)(b * CCH + c0)) * HW;
  float* dst = (z == 0 ? vmainT : vauxT) + (((size_t)(b * CCH + c0)) << 9);

  // per-point patch geometry, once per block (same point set for all channels)
  int t500 = (tid < NSEL) ? tid : 0;
  int p = idx[b * NPAD + t500];
  float wx[7], wy[7];
  int xc[7], yc[7], rb[7];
  patch_weights(p, xc, yc, wx, wy);
#pragma unroll
  for (int d = 0; d < 7; d++) rb[d] = yc[d] * WID;

  // prologue: DMA plane 0 into buffer 0
#pragma unroll
  for (int j = 0; j < 8; j++) {
    int off = (tid + j * 512) * 4;
    __builtin_amdgcn_global_load_lds(
        (const __attribute__((address_space(1))) float*)(src + off),
        (__attribute__((address_space(3))) float*)(plane2 + off), 16, 0, 0);
  }
  __syncthreads();  // drains vmcnt(0): plane 0 resident

  for (int c = 0; c < CPG; c++) {
    float* cur = plane2 + ((c & 1) ? HW : 0);
    float* nxt = plane2 + ((c & 1) ? 0 : HW);
    if (c + 1 < CPG) {
      // issue next plane's DMA: flies under the gather below
      const float* s2 = src + (size_t)(c + 1) * HW;
#pragma unroll
      for (int j = 0; j < 8; j++) {
        int off = (tid + j * 512) * 4;
        __builtin_amdgcn_global_load_lds(
            (const __attribute__((address_space(1))) float*)(s2 + off),
            (__attribute__((address_space(3))) float*)(nxt + off), 16, 0, 0);
      }
    }
    // gather current plane from LDS
    if (tid < NSEL) {
      float s = 0.f, mx = -INFINITY;
#pragma unroll
      for (int dy = 0; dy < 7; dy++) {
        float rs = 0.f, rm = -INFINITY;
        int rbb = rb[dy];
        float wyd = wy[dy];
#pragma unroll
        for (int dx = 0; dx < 7; dx++) {
          float v = cur[rbb + xc[dx]] * wx[dx];
          rs += v;
          rm = fmaxf(rm, v);
        }
        s += rs * wyd;
        mx = fmaxf(mx, rm * wyd);
      }
      dst[((size_t)c << 9) + tid] = 0.5f * (s * (1.f / 49.f) + mx);
    } else {
      dst[((size_t)c << 9) + tid] = 0.f;  // zero pad rows: no 0*garbage downstream
    }
    __syncthreads();  // all waves done with cur; nxt DMA drained (vmcnt(0))
  }
}

// ---------- tiled fp32 GEMM: C[b] = A[b](MxK) * B(KxN) ----------
// AT: A stored K-major (KxM). BT: B stored transposed (NxK). BSHARED: B not batched.
// EPI 0: plain store; 1: *0.0625; 2: +bias[col], store transposed [b][N][M]
// Register double-buffer: next k-tile's global loads issue right after the first
// barrier and complete under the FMA block (these GEMMs run at 1-2 blocks/CU, so
// the ~900cy load chain was fully exposed before).
template <int M, int N, int K, bool AT, bool BT, bool BSHARED, int EPI>
__global__ __launch_bounds__(256) void gemm_kernel(const float* __restrict__ A,
                                                   const float* __restrict__ B,
                                                   float* __restrict__ C,
                                                   const float* __restrict__ bias) {
  constexpr int BM = 64, BN = 64, BK = 16;
  __shared__ float As[BK][BM + 4];
  __shared__ float Bs[BK][BN + 4];
  int tid = threadIdx.x;
  int bx = blockIdx.x, by = blockIdx.y, b = blockIdx.z;
  const float* Ab = A + (size_t)b * M * K;
  const float* Bb = BSHARED ? B : (B + (size_t)b * ((size_t)K * N));
  int tx = tid & 15, ty = tid >> 4;
  float acc[4][4] = {};
  // staging-role indices
  int ar = tid >> 2, ac4 = (tid & 3) * 4;   // A row-major
  int kr = tid >> 4, mc = (tid & 15) * 4;   // A K-major
  int br = tid >> 4, bc4 = (tid & 15) * 4;  // B row-major
  int nr = tid >> 2, kc4 = (tid & 3) * 4;   // B transposed

  auto loadA = [&](int k0) -> float4 {
    if (!AT) return *(const float4*)&Ab[(size_t)(by * BM + ar) * K + k0 + ac4];
    else     return *(const float4*)&Ab[(size_t)(k0 + kr) * M + by * BM + mc];
  };
  auto loadB = [&](int k0) -> float4 {
    if (!BT) return *(const float4*)&Bb[(size_t)(k0 + br) * N + bx * BN + bc4];
    else     return *(const float4*)&Bb[(size_t)(bx * BN + nr) * K + k0 + kc4];
  };

  float4 avr = loadA(0), bvr = loadB(0);
  for (int k0 = 0; k0 < K; k0 += BK) {
    if (!AT) {
      As[ac4 + 0][ar] = avr.x; As[ac4 + 1][ar] = avr.y;
      As[ac4 + 2][ar] = avr.z; As[ac4 + 3][ar] = avr.w;
    } else {
      *(float4*)&As[kr][mc] = avr;
    }
    if (!BT) {
      *(float4*)&Bs[br][bc4] = bvr;
    } else {
      Bs[kc4 + 0][nr] = bvr.x; Bs[kc4 + 1][nr] = bvr.y;
      Bs[kc4 + 2][nr] = bvr.z; Bs[kc4 + 3][nr] = bvr.w;
    }
    __syncthreads();
    if (k0 + BK < K) { avr = loadA(k0 + BK); bvr = loadB(k0 + BK); }
#pragma unroll
    for (int kk = 0; kk < BK; kk++) {
      const float4 a = *(const float4*)&As[kk][ty * 4];
      const float4 bb = *(const float4*)&Bs[kk][tx * 4];
      float av[4] = {a.x, a.y, a.z, a.w};
      float bv[4] = {bb.x, bb.y, bb.z, bb.w};
#pragma unroll
      for (int rr = 0; rr < 4; rr++)
#pragma unroll
        for (int ss = 0; ss < 4; ss++) acc[rr][ss] += av[rr] * bv[ss];
    }
    __syncthreads();
  }
  if (EPI == 2) {
#pragma unroll
    for (int s = 0; s < 4; s++) {
      int col = bx * BN + tx * 4 + s;
      float bv = bias[col];
#pragma unroll
      for (int r = 0; r < 4; r++) {
        int row = by * BM + ty * 4 + r;
        C[((size_t)b * N + col) * M + row] = acc[r][s] + bv;
      }
    }
  } else {
    float scale = (EPI == 1) ? 0.0625f : 1.f;  // 1/sqrt(256)
#pragma unroll
    for (int r = 0; r < 4; r++) {
      int row = by * BM + ty * 4 + r;
#pragma unroll
      for (int s = 0; s < 4; s++) {
        int col = bx * BN + tx * 4 + s;
        C[((size_t)b * M + row) * N + col] = acc[r][s] * scale;
      }
    }
  }
}

// ---------- softmax over j (masked to j<NSEL), in place ----------
__global__ __launch_bounds__(256) void softmax_kernel(float* __restrict__ sim) {
  int i = blockIdx.x, b = blockIdx.y, tid = threadIdx.x;
  float* row = sim + ((size_t)b * NPAD + i) * NPAD;
  float v0 = (tid < NSEL) ? row[tid] : -INFINITY;
  int j1 = tid + 256;
  float v1 = (j1 < NSEL) ? row[j1] : -INFINITY;
  float m = fmaxf(v0, v1);
  for (int o = 32; o; o >>= 1) m = fmaxf(m, __shfl_down(m, o));
  __shared__ float red[4];
  __shared__ float bm, bs;
  int wave = tid >> 6, lane = tid & 63;
  if (lane == 0) red[wave] = m;
  __syncthreads();
  if (tid == 0) bm = fmaxf(fmaxf(red[0], red[1]), fmaxf(red[2], red[3]));
  __syncthreads();
  m = bm;
  float e0 = (tid < NSEL) ? expf(v0 - m) : 0.f;
  float e1 = (j1 < NSEL) ? expf(v1 - m) : 0.f;
  float s = e0 + e1;
  for (int o = 32; o; o >>= 1) s += __shfl_down(s, o);
  if (lane == 0) red[wave] = s;
  __syncthreads();
  if (tid == 0) bs = 1.f / (red[0] + red[1] + red[2] + red[3]);
  __syncthreads();
  row[tid] = e0 * bs;
  row[j1] = e1 * bs;
}

// ---------- gated-fusion MLP: vfused = vm + gate*(vm - vhat) ----------
// vm from channel-major vmainT[b][c][i]; vhat row-major [b][i][c]
// fc1 reduction via LDS transpose instead of 96 ds_bpermute shuffles.
__global__ __launch_bounds__(256) void mlp_kernel(const float* __restrict__ vmainT,
                                                  const float* __restrict__ vhat,
                                                  const float* __restrict__ fc1w,
                                                  const float* __restrict__ fc1b,
                                                  const float* __restrict__ fc2w,
                                                  const float* __restrict__ fc2b,
                                                  float* __restrict__ vfused) {
  int i = blockIdx.x, b = blockIdx.y, c = threadIdx.x;
  size_t base = ((size_t)b * NPAD + i) * CCH + c;
  float vm = vmainT[(((size_t)(b * CCH + c)) << 9) + i];
  float vh = vhat[base], vd = vm - vh;
  const float* w0 = fc1w + (size_t)c * 16;
  const float* w1 = fc1w + (size_t)(256 + c) * 16;
  const float* w2 = fc1w + (size_t)(512 + c) * 16;
  __shared__ float ph[256][17];    // [c][k], +1 pad: conflict-free both axes
  __shared__ float part2[16][17];  // [group][k]
  __shared__ float hsh[16];
#pragma unroll
  for (int k = 0; k < 16; k++) ph[c][k] = vm * w0[k] + vh * w1[k] + vd * w2[k];
  __syncthreads();
  int kk = c & 15, g = c >> 4;
  float part = 0.f;
#pragma unroll
  for (int j = 0; j < 16; j++) part += ph[g * 16 + j][kk];
  part2[g][kk] = part;
  __syncthreads();
  if (c < 16) {
    float s = fc1b[c];
#pragma unroll
    for (int g2 = 0; g2 < 16; g2++) s += part2[g2][c];
    hsh[c] = fmaxf(s, 0.f);
  }
  __syncthreads();
  float gte = fc2b[c];
#pragma unroll
  for (int k = 0; k < 16; k++) gte += hsh[k] * fc2w[k * 256 + c];
  gte = 1.f / (1.f + expf(-gte));
  vfused[base] = vm + gte * vd;
}

// ---------- K5: sparse scatter out[b,c,pix[s]] += vinjT[b,c,s] ----------
// out already holds the x_main copy (score_copy_kernel). Only ~3% of pixels
// are touched: ~100 MB of line traffic vs the old dense 1073 MB pass.
__global__ __launch_bounds__(256) void scatter_kernel(const int* __restrict__ idx,
                                                      const float* __restrict__ vinjT,
                                                      float* __restrict__ out) {
  int c = blockIdx.x, b = blockIdx.y, t = threadIdx.x;
  float* op = out + ((size_t)(b * CCH + c) << 14);
  const float* vp = vinjT + ((size_t)(b * CCH + c) << 9);
  const int* ib = idx + b * NPAD;
  // s = t (0..255 all valid) and s = t+256 (guard at 500)
  op[ib[t]] += vp[t];
  int s = t + 256;
  if (s < NSEL) op[ib[s]] += vp[s];
}

extern "C" void kernel_launch(void* const* d_in, const int* in_sizes, int n_in,
                              void* d_out, int out_size, void* d_ws, size_t ws_size,
                              hipStream_t stream) {
  const float* x_main   = (const float*)d_in[0];
  const float* x_aux    = (const float*)d_in[1];
  const float* scorer_w = (const float*)d_in[2];
  // d_in[3] scorer_b: constant shift, irrelevant to top-k set -> unused
  const float* fc1_w = (const float*)d_in[4];
  const float* fc1_b = (const float*)d_in[5];
  const float* fc2_w = (const float*)d_in[6];
  const float* fc2_b = (const float*)d_in[7];
  const float* proj_w = (const float*)d_in[8];
  const float* proj_b = (const float*)d_in[9];
  // d_in[10] n == 500 (fixed)
  (void)in_sizes; (void)n_in; (void)out_size; (void)ws_size;

  float* ws = (float*)d_ws;
  // workspace layout (floats), ~26 MB total
  float* logits = ws;                      // 131072
  int*   idx    = (int*)(ws + 131072);     // 4096
  float* vmainT = ws + 266240;             // 1048576  [b][c][i]
  float* vauxT  = ws + 1314816;            // 1048576  [b][c][i]
  float* vhat   = ws + 2363392;            // 1048576  [b][i][c] (v_injT reuses this)
  float* vfused = ws + 3411968;            // 1048576  [b][i][c]
  float* sim    = ws + 4460544;            // 2097152  [b][i][j]
  float* vinjT  = vhat;
  float* out = (float*)d_out;

  score_copy_kernel<<<512, 256, 0, stream>>>(x_main, scorer_w, logits, out);
  topk_kernel<<<NB, 1024, 0, stream>>>(logits, idx);
  gather_dma_kernel<<<dim3(CCH / CPG, NB, 2), 512, 2 * HW * sizeof(float), stream>>>(
      x_main, x_aux, idx, vmainT, vauxT);
  // sim[b][i][j] = sum_c vmainT[b][c][i] * vauxT[b][c][j] / 16   (TN gemm)
  gemm_kernel<NPAD, NPAD, CCH, true, false, false, 1>
      <<<dim3(8, 8, NB), 256, 0, stream>>>(vmainT, vauxT, sim, nullptr);
  softmax_kernel<<<dim3(NPAD, NB), 256, 0, stream>>>(sim);
  // v_hat[b][i][c] = sum_j attn[b][i][j] * vauxT[b][c][j]   (B transposed)
  gemm_kernel<NPAD, CCH, NPAD, false, true, false, 0>
      <<<dim3(4, 8, NB), 256, 0, stream>>>(sim, vauxT, vhat, nullptr);
  mlp_kernel<<<dim3(NPAD, NB), 256, 0, stream>>>(vmainT, vhat, fc1_w, fc1_b,
                                                 fc2_w, fc2_b, vfused);
  // v_injT[b][c][i] = (v_fused @ proj_w + proj_b)^T
  gemm_kernel<NPAD, CCH, CCH, false, false, true, 2>
      <<<dim3(4, 8, NB), 256, 0, stream>>>(vfused, proj_w, vinjT, proj_b);
  scatter_kernel<<<dim3(CCH, NB), 256, 0, stream>>>(idx, vinjT, out);
}